// Round 13
// baseline (6453.593 us; speedup 1.0000x reference)
//
#include <hip/hip_runtime.h>
#include <hip/hip_bf16.h>

typedef __attribute__((ext_vector_type(8))) short bf16x8;
typedef __attribute__((ext_vector_type(4))) float f32x4;

#define MFMA16(a,b,c) __builtin_amdgcn_mfma_f32_16x16x32_bf16(a,b,c,0,0,0)

__device__ inline ushort f2bf(float f){
  union { float f; uint u; } v; v.f = f;
  uint r = v.u + 0x7FFFu + ((v.u >> 16) & 1u);
  return (ushort)(r >> 16);
}
__device__ inline float sigf(float x){ return 1.f/(1.f+__expf(-x)); }
__device__ inline float tanhf_(float x){ return 2.f/(1.f+__expf(-2.f*x)) - 1.f; }

__device__ inline void gload_lds16(const ushort* g, ushort* lds){
  __builtin_amdgcn_global_load_lds(
      (const __attribute__((address_space(1))) void*)g,
      (__attribute__((address_space(3))) void*)lds, 16, 0, 0);
}

struct PK {
  const float *obs, *obsVel, *mean, *stdv, *encW, *encb, *decW, *decb;
  const float *lstm_Wih, *lstm_Whh, *lstm_b, *cell_Wih, *cell_Whh, *cell_b;
  ushort *wbf, *embed, *h0a, *h0b, *h1a, *h1b;
  float *c0, *c1;
  ushort *pred;
  float *out;
  uint *bar;       // 2 uints: {counter, generation} — lives in d_out[0..1]
};

// ---- software grid barrier: 512 blocks, all co-resident (2/CU x 256 CU) ----
__device__ __forceinline__ void gbar(uint* bar){
  __threadfence();                       // release: h/C stores -> device scope
  __syncthreads();
  if (threadIdx.x == 0){
    uint g = __hip_atomic_load(&bar[1], __ATOMIC_RELAXED, __HIP_MEMORY_SCOPE_AGENT);
    uint a = __hip_atomic_fetch_add(&bar[0], 1u, __ATOMIC_ACQ_REL, __HIP_MEMORY_SCOPE_AGENT);
    if (a == 511u){
      __hip_atomic_store(&bar[0], 0u, __ATOMIC_RELAXED, __HIP_MEMORY_SCOPE_AGENT);
      __hip_atomic_store(&bar[1], g + 1u, __ATOMIC_RELEASE, __HIP_MEMORY_SCOPE_AGENT);
    } else {
      while (__hip_atomic_load(&bar[1], __ATOMIC_ACQUIRE, __HIP_MEMORY_SCOPE_AGENT) == g)
        __builtin_amdgcn_s_sleep(2);
    }
  }
  __syncthreads();
  __threadfence();                       // acquire: invalidate stale L1/L2
}

// ---- r10 cell body (best proven variant, verbatim structure) ----
#define NKT_SEG 8

__device__ __forceinline__ void cell_body(
    const ushort* __restrict__ A0, int lda0,
    const ushort* __restrict__ A1,
    const ushort* __restrict__ B0,
    const ushort* __restrict__ B1,
    const float*  __restrict__ bias,
    float* __restrict__ C,
    ushort* __restrict__ H0,
    ushort* __restrict__ H1,
    int nSeg, int czero,
    ushort (*bL)[8192], int tid, int blk)
{
  const int w = tid >> 6, lane = tid & 63;
  const int bm = (blk >> 4) * 128;
  const int bn = (blk & 15) * 32;

  const int r0 = bm + w*32 + ((lane>>4)<<2);
  float br[2][4], creg[2][2][4];
  #pragma unroll
  for (int cc=0;cc<2;cc++){
    const int ccol = bn + cc*16 + (lane&15);
    br[cc][0] = bias[ccol];
    br[cc][1] = bias[512+ccol];
    br[cc][2] = bias[1024+ccol];
    br[cc][3] = bias[1536+ccol];
  }
  if (czero){
    #pragma unroll
    for (int cc=0;cc<2;cc++)
      #pragma unroll
      for (int m=0;m<2;m++)
        #pragma unroll
        for (int reg=0;reg<4;reg++) creg[cc][m][reg] = 0.f;
  } else {
    #pragma unroll
    for (int cc=0;cc<2;cc++){
      const int ccol = bn + cc*16 + (lane&15);
      #pragma unroll
      for (int m=0;m<2;m++)
        #pragma unroll
        for (int reg=0;reg<4;reg++)
          creg[cc][m][reg] = C[(size_t)(r0 + m*16 + reg)*512 + ccol];
    }
  }

  f32x4 acc[2][8];
  #pragma unroll
  for (int m=0;m<2;m++)
    #pragma unroll
    for (int n=0;n<8;n++) acc[m][n] = (f32x4)0.f;

  int boff[4], ldsO[4];
  #pragma unroll
  for (int p=0;p<4;p++){
    int i = p*256 + tid;
    int r = i>>3, s = i&7, ch = s ^ (r&7);
    boff[p] = (((r>>5)<<9) + bn + (r&31))*512 + ch*8;
    ldsO[p] = (p*256 + (tid & ~63)) * 8;
  }

  const int arow0 = bm + w*32 + (lane&15);
  const int arow1 = arow0 + 16;
  const int ca = (lane>>4)*8;

  int bOff[8];
  #pragma unroll
  for (int n=0;n<8;n++){
    int row = (n>>1)*32 + (n&1)*16 + (lane&15);
    int slot = (lane>>4) ^ (row&7);
    bOff[n] = row*64 + slot*8;
  }

  #define STAGE_B(bi, kt) do { \
    const ushort* Bseg = ((kt) < NKT_SEG) ? B0 : B1; \
    const int k0_ = ((kt) & (NKT_SEG-1)) << 6; \
    _Pragma("unroll") \
    for (int p=0;p<4;p++) \
      gload_lds16(Bseg + boff[p] + k0_, &bL[bi][ldsO[p]]); \
  } while(0)

  #define LOAD_A(AF, kt) do { \
    const ushort* Aseg = ((kt) < NKT_SEG) ? A0 : A1; \
    const int lda_     = ((kt) < NKT_SEG) ? lda0 : 512; \
    const int k0_ = (((kt) & (NKT_SEG-1)) << 6) + ca; \
    const ushort* pa0_ = Aseg + (size_t)arow0*lda_ + k0_; \
    const ushort* pa1_ = Aseg + (size_t)arow1*lda_ + k0_; \
    AF[0][0] = *(const bf16x8*)pa0_;  AF[0][1] = *(const bf16x8*)(pa0_+32); \
    AF[1][0] = *(const bf16x8*)pa1_;  AF[1][1] = *(const bf16x8*)(pa1_+32); \
  } while(0)

  #define COMPUTE(bi, AF) do { \
    bf16x8 bfr[8]; \
    _Pragma("unroll") \
    for (int n=0;n<8;n++) bfr[n] = *(const bf16x8*)&bL[bi][bOff[n]]; \
    __builtin_amdgcn_s_setprio(1); \
    _Pragma("unroll") \
    for (int m=0;m<2;m++) \
      _Pragma("unroll") \
      for (int n=0;n<8;n++) acc[m][n] = MFMA16(AF[m][0], bfr[n], acc[m][n]); \
    __builtin_amdgcn_s_setprio(0); \
    _Pragma("unroll") \
    for (int n=0;n<8;n++) bfr[n] = *(const bf16x8*)&bL[bi][bOff[n]^32]; \
    __builtin_amdgcn_s_setprio(1); \
    _Pragma("unroll") \
    for (int m=0;m<2;m++) \
      _Pragma("unroll") \
      for (int n=0;n<8;n++) acc[m][n] = MFMA16(AF[m][1], bfr[n], acc[m][n]); \
    __builtin_amdgcn_s_setprio(0); \
  } while(0)

  #define SYNC_CNT(N) do { \
    __builtin_amdgcn_sched_barrier(0); \
    asm volatile("s_waitcnt vmcnt(" #N ")" ::: "memory"); \
    __builtin_amdgcn_s_barrier(); \
    __builtin_amdgcn_sched_barrier(0); \
  } while(0)

  const int nkt = nSeg * NKT_SEG;
  bf16x8 aA[2][2], aB[2][2];
  int b0 = 0, b1 = 1, b2 = 2;

  STAGE_B(0, 0);
  STAGE_B(1, 1);
  LOAD_A(aA, 0);
  SYNC_CNT(8);

  for (int kt = 0; kt < nkt-2; kt += 2){
    STAGE_B(b2, kt+2);
    LOAD_A(aB, kt+1);
    COMPUTE(b0, aA);
    SYNC_CNT(8);
    { int t_ = b0; b0 = b1; b1 = b2; b2 = t_; }
    STAGE_B(b2, kt+3 < nkt ? kt+3 : kt+2);
    LOAD_A(aA, kt+2);
    COMPUTE(b0, aB);
    SYNC_CNT(8);
    { int t_ = b0; b0 = b1; b1 = b2; b2 = t_; }
  }
  LOAD_A(aB, nkt-1);
  COMPUTE(b0, aA);
  SYNC_CNT(4);
  COMPUTE(b1, aB);

  #undef STAGE_B
  #undef LOAD_A
  #undef COMPUTE
  #undef SYNC_CNT

  #pragma unroll
  for (int cc=0;cc<2;cc++){
    const int ccol = bn + cc*16 + (lane&15);
    const float bi = br[cc][0], bff = br[cc][1], bg = br[cc][2], bo = br[cc][3];
    #pragma unroll
    for (int m=0;m<2;m++){
      #pragma unroll
      for (int reg=0;reg<4;reg++){
        const int row = r0 + m*16 + reg;
        float gi = acc[m][0+cc][reg] + bi;
        float gf = acc[m][2+cc][reg] + bff;
        float gg = acc[m][4+cc][reg] + bg;
        float go = acc[m][6+cc][reg] + bo;
        float cn = sigf(gf)*creg[cc][m][reg] + sigf(gi)*tanhf_(gg);
        float hv = sigf(go)*tanhf_(cn);
        C[(size_t)row*512 + ccol] = cn;
        ushort hb = f2bf(hv);
        H0[(size_t)row*512 + ccol] = hb;
        if (H1) H1[(size_t)row*6144 + ccol] = hb;
      }
    }
  }
}

__global__ __launch_bounds__(256, 2) void persistent_kernel(PK p){
  __shared__ ushort bL[3][8192];
  const int tid = threadIdx.x;
  const int blk = blockIdx.x;

  // ---- phase 0: convert weights (fp32->bf16) + embed ----
  {
    #pragma unroll 1
    for (int rep=0; rep<16; ++rep){
      size_t i4 = (((size_t)rep*512 + blk)*256 + tid)*4;
      int tsel = (int)(i4 >> 21);
      const float* s = (tsel & 2) ? ((tsel & 1) ? p.cell_Whh : p.cell_Wih)
                                  : ((tsel & 1) ? p.lstm_Whh : p.lstm_Wih);
      size_t off = i4 & 2097151u;
      float4 v = *(const float4*)&s[off];
      ushort4 o; o.x=f2bf(v.x); o.y=f2bf(v.y); o.z=f2bf(v.z); o.w=f2bf(v.w);
      *(ushort4*)&p.wbf[i4] = o;
    }
    const float m0=p.mean[0], m1=p.mean[1], s0=p.stdv[0], s1=p.stdv[1];
    #pragma unroll 1
    for (int rep=0; rep<16; ++rep){
      int idx = (rep*512 + blk)*256 + tid;
      int row = idx >> 6, c8 = (idx & 63) * 8;
      float x0 = (p.obsVel[row*2+0] - m0) / s0;
      float x1 = (p.obsVel[row*2+1] - m1) / s1;
      ushort o[8];
      #pragma unroll
      for (int j=0;j<8;j++){
        int col = c8 + j;
        o[j] = f2bf(x0*p.encW[col] + x1*p.encW[512+col] + p.encb[col]);
      }
      *(uint4*)&p.embed[(size_t)row*512 + c8] = *(const uint4*)o;
    }
  }
  gbar(p.bar);

  const ushort* wl_ih = p.wbf;
  const ushort* wl_hh = p.wbf + 2097152;
  const ushort* wc_ih = p.wbf + 4194304;
  const ushort* wc_hh = p.wbf + 6291456;

  ushort* h0buf[2] = {p.h0a, p.h0b};
  ushort* h1buf[2] = {p.h1a, p.h1b};
  int cur0 = 0, cur1 = 0;

  #pragma unroll 1
  for (int ph=0; ph<38; ++ph){
    const int s = ph >> 1, layer = ph & 1;
    const bool enc = s < 8;
    const int ns = (s==0) ? 1 : 2, cz = (s==0) ? 1 : 0;
    const ushort *A0, *A1, *B0, *B1;
    const float *bias; float *C; ushort *H0, *H1; int lda0;
    if (layer == 0){
      A0 = enc ? p.embed + s*512 : p.pred + (s-8)*512;
      lda0 = enc ? 4096 : 6144;
      A1 = h0buf[cur0];
      B0 = enc ? wl_ih : wc_ih;  B1 = enc ? wl_hh : wc_hh;
      bias = enc ? p.lstm_b : p.cell_b;
      C = p.c0; H0 = h0buf[cur0^1]; H1 = nullptr;
    } else {
      A0 = h0buf[cur0^1]; lda0 = 512;
      A1 = h1buf[cur1];
      B0 = (enc ? wl_ih : wc_ih) + 1048576;  B1 = (enc ? wl_hh : wc_hh) + 1048576;
      bias = (enc ? p.lstm_b : p.cell_b) + 2048;
      C = p.c1; H0 = h1buf[cur1^1];
      H1 = enc ? (s==7 ? p.pred : nullptr) : p.pred + (s-7)*512;
    }
    cell_body(A0, lda0, A1, B0, B1, bias, C, H0, H1, ns, cz, bL, tid, blk);
    gbar(p.bar);
    if (layer == 1){ cur0 ^= 1; cur1 ^= 1; }
  }

  // ---- final: projection + cumsum (8 batches per block) ----
  {
    const int w = tid >> 6, lane = tid & 63;
    float w0[8], w1[8];
    #pragma unroll
    for (int j=0;j<8;j++){
      int k = lane*8 + j;
      w0[j] = p.decW[k*2+0];
      w1[j] = p.decW[k*2+1];
    }
    const float m0=p.mean[0], m1=p.mean[1], sv0=p.stdv[0], sv1=p.stdv[1];
    const float db0=p.decb[0], db1=p.decb[1];
    #pragma unroll 1
    for (int rep=0; rep<2; ++rep){
      const int b = blk*8 + rep*4 + w;
      float cum0 = 0.f, cum1 = 0.f;
      const float o0 = p.obs[(b*8+7)*2+0], o1 = p.obs[(b*8+7)*2+1];
      for (int t=0;t<12;t++){
        const uint4 q = *(const uint4*)&p.pred[((size_t)b*12+t)*512 + lane*8];
        uint u[4] = {q.x,q.y,q.z,q.w};
        float s0=0.f, s1=0.f;
        #pragma unroll
        for (int pp=0;pp<4;pp++){
          float lo = __uint_as_float(u[pp]<<16);
          float hi = __uint_as_float(u[pp]&0xffff0000u);
          s0 += lo*w0[2*pp] + hi*w0[2*pp+1];
          s1 += lo*w1[2*pp] + hi*w1[2*pp+1];
        }
        #pragma unroll
        for (int off=32; off>0; off>>=1){ s0 += __shfl_down(s0, off); s1 += __shfl_down(s1, off); }
        if (lane==0){
          cum0 += (s0+db0)*sv0 + m0;
          cum1 += (s1+db1)*sv1 + m1;
          p.out[((size_t)b*12+t)*2+0] = cum0 + o0;
          p.out[((size_t)b*12+t)*2+1] = cum1 + o1;
        }
      }
    }
  }
}

extern "C" void kernel_launch(void* const* d_in, const int* in_sizes, int n_in,
                              void* d_out, int out_size, void* d_ws, size_t ws_size,
                              hipStream_t stream) {
  char* ws = (char*)d_ws;
  PK p;
  p.obs      = (const float*)d_in[0];
  p.obsVel   = (const float*)d_in[1];
  p.mean     = (const float*)d_in[2];
  p.stdv     = (const float*)d_in[3];
  p.encW     = (const float*)d_in[5];
  p.encb     = (const float*)d_in[6];
  p.decW     = (const float*)d_in[7];
  p.decb     = (const float*)d_in[8];
  p.lstm_Wih = (const float*)d_in[9];
  p.lstm_Whh = (const float*)d_in[10];
  p.lstm_b   = (const float*)d_in[11];
  p.cell_Wih = (const float*)d_in[12];
  p.cell_Whh = (const float*)d_in[13];
  p.cell_b   = (const float*)d_in[14];
  p.wbf   = (ushort*)ws;                       // 16 MB
  p.embed = (ushort*)(ws + (16ull<<20));       // 32 MB
  p.h0a   = (ushort*)(ws + (48ull<<20));
  p.h0b   = (ushort*)(ws + (52ull<<20));
  p.h1a   = (ushort*)(ws + (56ull<<20));
  p.h1b   = (ushort*)(ws + (60ull<<20));
  p.c0    = (float*)(ws + (64ull<<20));
  p.c1    = (float*)(ws + (72ull<<20));
  p.pred  = (ushort*)(ws + (80ull<<20));       // 48 MB
  p.out   = (float*)d_out;
  p.bar   = (uint*)d_out;                      // first 8 bytes; overwritten at end

  // zero the barrier {counter, gen} every call (graph-capture-safe)
  hipMemsetAsync(d_out, 0, 8, stream);

  persistent_kernel<<<dim3(512), dim3(256), 0, stream>>>(p);
}

// Round 14
// 1537.791 us; speedup vs baseline: 4.1967x; 4.1967x over previous
//
#include <hip/hip_runtime.h>
#include <hip/hip_bf16.h>

typedef __attribute__((ext_vector_type(8))) short bf16x8;
typedef __attribute__((ext_vector_type(4))) float f32x4;

#define MFMA16(a,b,c) __builtin_amdgcn_mfma_f32_16x16x32_bf16(a,b,c,0,0,0)

__device__ inline ushort f2bf(float f){
  union { float f; uint u; } v; v.f = f;
  uint r = v.u + 0x7FFFu + ((v.u >> 16) & 1u);
  return (ushort)(r >> 16);
}
__device__ inline float sigf(float x){ return 1.f/(1.f+__expf(-x)); }
__device__ inline float tanhf_(float x){ return 2.f/(1.f+__expf(-2.f*x)) - 1.f; }

__device__ inline void gload_lds16(const ushort* g, ushort* lds){
  __builtin_amdgcn_global_load_lds(
      (const __attribute__((address_space(1))) void*)g,
      (__attribute__((address_space(3))) void*)lds, 16, 0, 0);
}

// ---------------- weight fp32 -> bf16 conversion ----------------
__global__ void convert_weights(const float* __restrict__ s0, const float* __restrict__ s1,
                                const float* __restrict__ s2, const float* __restrict__ s3,
                                ushort* __restrict__ dst){
  size_t i4 = ((size_t)blockIdx.x*256 + threadIdx.x)*4;
  int tsel = (int)(i4 >> 21);
  const float* s = (tsel & 2) ? ((tsel & 1) ? s3 : s2) : ((tsel & 1) ? s1 : s0);
  size_t off = i4 & 2097151u;
  float4 v = *(const float4*)&s[off];
  ushort4 o; o.x=f2bf(v.x); o.y=f2bf(v.y); o.z=f2bf(v.z); o.w=f2bf(v.w);
  *(ushort4*)&dst[i4] = o;
}

// ---------------- embed ----------------
__global__ void embed_kernel(const float* __restrict__ obsVel, const float* __restrict__ mean,
                             const float* __restrict__ stdv, const float* __restrict__ encW,
                             const float* __restrict__ encb, ushort* __restrict__ embed){
  int idx = blockIdx.x*256 + threadIdx.x;   // < 32768*64
  int row = idx >> 6, c8 = (idx & 63) * 8;
  float x0 = (obsVel[row*2+0] - mean[0]) / stdv[0];
  float x1 = (obsVel[row*2+1] - mean[1]) / stdv[1];
  ushort o[8];
  #pragma unroll
  for (int j=0;j<8;j++){
    int col = c8 + j;
    o[j] = f2bf(x0*encW[col] + x1*encW[512+col] + encb[col]);
  }
  *(uint4*)&embed[(size_t)row*512 + c8] = *(const uint4*)o;
}

// ---------------- fused LSTM cell step ----------------
// r10 pipeline, quarter-width N-tile for 2x TLP: grid (32,32) = 1024 blocks
// = 4 blocks/CU = 16 waves/CU. Block tile 128 rows x (4 gates x 16 cols).
// 256 thr = 4 waves M-stacked (wave: 32 rows x 64 gcols; frag n = gate ->
// gates in-lane, epilogue unchanged). BK=64. A: direct global->reg, 1-iter
// prefetch. B: LDS 3 bufs x 8 KB = 24 KB, depth-2 counted-vmcnt staging,
// raw s_barrier (no vmcnt(0) drain). Swizzle slot = ch ^ (row&7) (0-conflict).
#define NKT_SEG 8   // K=512 per segment / BK=64

__global__ __launch_bounds__(256, 2) void lstm_cell_kernel(
    const ushort* __restrict__ A0, int lda0,
    const ushort* __restrict__ A1, int lda1,
    const ushort* __restrict__ B0,
    const ushort* __restrict__ B1,
    const float*  __restrict__ bias,
    float* __restrict__ C,
    ushort* __restrict__ H0, int ldh0,
    ushort* __restrict__ H1, int ldh1,
    int nSeg, int czero)
{
  __shared__ ushort bL[3][4096];   // 64 B-rows x 64 k bf16 per buf, swizzled
  const int tid = threadIdx.x;
  const int w = tid >> 6, lane = tid & 63;
  const int bm = blockIdx.y * 128;
  const int bn = blockIdx.x * 16;            // gate-local col base (16 wide)

  // ---- epilogue operand prefetch (oldest VMEM; latency hidden by GEMM) ----
  const int r0 = bm + w*32 + ((lane>>4)<<2);
  const int ccol = bn + (lane&15);           // gate-local col
  float br[4], creg[2][4];
  #pragma unroll
  for (int g=0;g<4;g++) br[g] = bias[g*512 + ccol];
  if (czero){
    #pragma unroll
    for (int m=0;m<2;m++)
      #pragma unroll
      for (int reg=0;reg<4;reg++) creg[m][reg] = 0.f;
  } else {
    #pragma unroll
    for (int m=0;m<2;m++)
      #pragma unroll
      for (int reg=0;reg<4;reg++)
        creg[m][reg] = C[(size_t)(r0 + m*16 + reg)*512 + ccol];
  }

  f32x4 acc[2][4];   // [m][gate]
  #pragma unroll
  for (int m=0;m<2;m++)
    #pragma unroll
    for (int g=0;g<4;g++) acc[m][g] = (f32x4)0.f;

  // ---- B staging: 2 chunks/thread/tile; inverse swizzle (0-conflict) ----
  // tile = 64 B-rows (4 gates x 16 cols) x 64 k. chunk i -> LDS byte i*16;
  // r = i>>3 (row), s = i&7 (slot), src k-chunk c = s ^ (r&7).
  int boff[2], ldsO[2];
  #pragma unroll
  for (int p=0;p<2;p++){
    int i = p*256 + tid;
    int r = i>>3, s = i&7, c = s ^ (r&7);
    boff[p] = (((r>>4)<<9) + bn + (r&15))*512 + c*8;   // elem offset in B seg
    ldsO[p] = (p*256 + (tid & ~63)) * 8;               // wave-uniform base
  }

  // ---- A direct-load geometry (wave-private rows) ----
  const int arow0 = bm + w*32 + (lane&15);
  const int arow1 = arow0 + 16;
  const int ca = (lane>>4)*8;

  // ---- B frag read offsets (ushort units); kk=1 -> ^32 ----
  int bOff[4];
  #pragma unroll
  for (int g=0;g<4;g++){
    int row = g*16 + (lane&15);
    int slot = (lane>>4) ^ (row&7);
    bOff[g] = row*64 + slot*8;
  }

  #define STAGE_B(bi, kt) do { \
    const ushort* Bseg = ((kt) < NKT_SEG) ? B0 : B1; \
    const int k0_ = ((kt) & (NKT_SEG-1)) << 6; \
    gload_lds16(Bseg + boff[0] + k0_, &bL[bi][ldsO[0]]); \
    gload_lds16(Bseg + boff[1] + k0_, &bL[bi][ldsO[1]]); \
  } while(0)

  #define LOAD_A(AF, kt) do { \
    const ushort* Aseg = ((kt) < NKT_SEG) ? A0 : A1; \
    const int lda_     = ((kt) < NKT_SEG) ? lda0 : lda1; \
    const int k0_ = (((kt) & (NKT_SEG-1)) << 6) + ca; \
    const ushort* pa0_ = Aseg + (size_t)arow0*lda_ + k0_; \
    const ushort* pa1_ = Aseg + (size_t)arow1*lda_ + k0_; \
    AF[0][0] = *(const bf16x8*)pa0_;  AF[0][1] = *(const bf16x8*)(pa0_+32); \
    AF[1][0] = *(const bf16x8*)pa1_;  AF[1][1] = *(const bf16x8*)(pa1_+32); \
  } while(0)

  #define COMPUTE(bi, AF) do { \
    _Pragma("unroll") \
    for (int kk=0;kk<2;kk++){ \
      bf16x8 bfr[4]; \
      _Pragma("unroll") \
      for (int g=0;g<4;g++) bfr[g] = *(const bf16x8*)&bL[bi][bOff[g] ^ (kk*32)]; \
      __builtin_amdgcn_s_setprio(1); \
      _Pragma("unroll") \
      for (int m=0;m<2;m++) \
        _Pragma("unroll") \
        for (int g=0;g<4;g++) acc[m][g] = MFMA16(AF[m][kk], bfr[g], acc[m][g]); \
      __builtin_amdgcn_s_setprio(0); \
    } \
  } while(0)

  #define SYNC_CNT(N) do { \
    __builtin_amdgcn_sched_barrier(0); \
    asm volatile("s_waitcnt vmcnt(" #N ")" ::: "memory"); \
    __builtin_amdgcn_s_barrier(); \
    __builtin_amdgcn_sched_barrier(0); \
  } while(0)

  const int nkt = nSeg * NKT_SEG;   // 8 or 16 (even)
  bf16x8 aA[2][2], aB[2][2];
  int b0 = 0, b1 = 1, b2 = 2;

  // prologue: stage 2 tiles, load A(0); wait only stage(0)
  // outstanding newer than stage(0): stage(1)=2 + A(0)=4 -> vmcnt(6)
  STAGE_B(0, 0);
  STAGE_B(1, 1);
  LOAD_A(aA, 0);
  SYNC_CNT(6);

  for (int kt = 0; kt < nkt-2; kt += 2){
    STAGE_B(b2, kt+2);
    LOAD_A(aB, kt+1);
    COMPUTE(b0, aA);
    SYNC_CNT(6);
    { int t_ = b0; b0 = b1; b1 = b2; b2 = t_; }
    STAGE_B(b2, kt+3 < nkt ? kt+3 : kt+2);
    LOAD_A(aA, kt+2);
    COMPUTE(b0, aB);
    SYNC_CNT(6);
    { int t_ = b0; b0 = b1; b1 = b2; b2 = t_; }
  }
  // tail: kt = nkt-2 (aA, buf b0), then nkt-1 (aB, buf b1)
  LOAD_A(aB, nkt-1);
  COMPUTE(b0, aA);
  SYNC_CNT(4);
  COMPUTE(b1, aB);

  #undef STAGE_B
  #undef LOAD_A
  #undef COMPUTE
  #undef SYNC_CNT

  // ---- epilogue: bias + gates, c update, h writes ----
  #pragma unroll
  for (int m=0;m<2;m++){
    #pragma unroll
    for (int reg=0;reg<4;reg++){
      const int row = r0 + m*16 + reg;
      float gi = acc[m][0][reg] + br[0];
      float gf = acc[m][1][reg] + br[1];
      float gg = acc[m][2][reg] + br[2];
      float go = acc[m][3][reg] + br[3];
      float cn = sigf(gf)*creg[m][reg] + sigf(gi)*tanhf_(gg);
      float hv = sigf(go)*tanhf_(cn);
      C[(size_t)row*512 + ccol] = cn;
      ushort hb = f2bf(hv);
      H0[(size_t)row*ldh0 + ccol] = hb;
      if (H1) H1[(size_t)row*ldh1 + ccol] = hb;
    }
  }
}

// ---------------- projection + cumsum ----------------
__global__ void final_kernel(const ushort* __restrict__ pred, const float* __restrict__ decW,
                             const float* __restrict__ decb, const float* __restrict__ mean,
                             const float* __restrict__ stdv, const float* __restrict__ obs,
                             float* __restrict__ out){
  int w = threadIdx.x >> 6, lane = threadIdx.x & 63;
  int b = blockIdx.x*4 + w;
  float w0[8], w1[8];
  #pragma unroll
  for (int j=0;j<8;j++){
    int k = lane*8 + j;
    w0[j] = decW[k*2+0];
    w1[j] = decW[k*2+1];
  }
  float cum0 = 0.f, cum1 = 0.f;
  float m0 = mean[0], m1 = mean[1], sv0 = stdv[0], sv1 = stdv[1];
  float o0 = obs[(b*8+7)*2+0], o1 = obs[(b*8+7)*2+1];
  float db0 = decb[0], db1 = decb[1];
  for (int t=0;t<12;t++){
    const uint4 q = *(const uint4*)&pred[((size_t)b*12+t)*512 + lane*8];
    uint u[4] = {q.x,q.y,q.z,q.w};
    float s0=0.f, s1=0.f;
    #pragma unroll
    for (int p=0;p<4;p++){
      float lo = __uint_as_float(u[p]<<16);
      float hi = __uint_as_float(u[p]&0xffff0000u);
      s0 += lo*w0[2*p] + hi*w0[2*p+1];
      s1 += lo*w1[2*p] + hi*w1[2*p+1];
    }
    #pragma unroll
    for (int off=32; off>0; off>>=1){ s0 += __shfl_down(s0, off); s1 += __shfl_down(s1, off); }
    if (lane==0){
      cum0 += (s0+db0)*sv0 + m0;
      cum1 += (s1+db1)*sv1 + m1;
      out[((size_t)b*12+t)*2+0] = cum0 + o0;
      out[((size_t)b*12+t)*2+1] = cum1 + o1;
    }
  }
}

extern "C" void kernel_launch(void* const* d_in, const int* in_sizes, int n_in,
                              void* d_out, int out_size, void* d_ws, size_t ws_size,
                              hipStream_t stream) {
  const float* obs      = (const float*)d_in[0];
  const float* obsVel   = (const float*)d_in[1];
  const float* mean     = (const float*)d_in[2];
  const float* stdv     = (const float*)d_in[3];
  const float* encW     = (const float*)d_in[5];
  const float* encb     = (const float*)d_in[6];
  const float* decW     = (const float*)d_in[7];
  const float* decb     = (const float*)d_in[8];
  const float* lstm_Wih = (const float*)d_in[9];
  const float* lstm_Whh = (const float*)d_in[10];
  const float* lstm_b   = (const float*)d_in[11];
  const float* cell_Wih = (const float*)d_in[12];
  const float* cell_Whh = (const float*)d_in[13];
  const float* cell_b   = (const float*)d_in[14];

  char* ws = (char*)d_ws;
  ushort* wbf   = (ushort*)ws;                       // 16 MB
  ushort* embed = (ushort*)(ws + (16ull<<20));       // 32 MB
  ushort* h0[2] = {(ushort*)(ws + (48ull<<20)), (ushort*)(ws + (52ull<<20))};
  ushort* h1[2] = {(ushort*)(ws + (56ull<<20)), (ushort*)(ws + (60ull<<20))};
  float*  c0    = (float*)(ws + (64ull<<20));
  float*  c1    = (float*)(ws + (72ull<<20));
  ushort* pred  = (ushort*)(ws + (80ull<<20));       // 48 MB

  ushort* w_lstm_ih = wbf;
  ushort* w_lstm_hh = wbf + 2097152;
  ushort* w_cell_ih = wbf + 4194304;
  ushort* w_cell_hh = wbf + 6291456;

  convert_weights<<<8192, 256, 0, stream>>>(lstm_Wih, lstm_Whh, cell_Wih, cell_Whh, wbf);
  embed_kernel<<<8192, 256, 0, stream>>>(obsVel, mean, stdv, encW, encb, embed);

  dim3 grid(32, 32);
  int cur0 = 0, cur1 = 0;
  for (int t=0;t<8;t++){
    int ns = (t==0) ? 1 : 2;
    int cz = (t==0) ? 1 : 0;
    lstm_cell_kernel<<<grid, 256, 0, stream>>>(embed + t*512, 4096, h0[cur0], 512,
        w_lstm_ih, w_lstm_hh, lstm_b, c0, h0[cur0^1], 512, (ushort*)nullptr, 0, ns, cz);
    lstm_cell_kernel<<<grid, 256, 0, stream>>>(h0[cur0^1], 512, h1[cur1], 512,
        w_lstm_ih + 1048576, w_lstm_hh + 1048576, lstm_b + 2048, c1, h1[cur1^1], 512,
        (t==7) ? pred : (ushort*)nullptr, 6144, ns, cz);
    cur0 ^= 1; cur1 ^= 1;
  }
  for (int s=1;s<12;s++){
    lstm_cell_kernel<<<grid, 256, 0, stream>>>(pred + (s-1)*512, 6144, h0[cur0], 512,
        w_cell_ih, w_cell_hh, cell_b, c0, h0[cur0^1], 512, (ushort*)nullptr, 0, 2, 0);
    lstm_cell_kernel<<<grid, 256, 0, stream>>>(h0[cur0^1], 512, h1[cur1], 512,
        w_cell_ih + 1048576, w_cell_hh + 1048576, cell_b + 2048, c1, h1[cur1^1], 512,
        pred + s*512, 6144, 2, 0);
    cur0 ^= 1; cur1 ^= 1;
  }
  final_kernel<<<1024, 256, 0, stream>>>(pred, decW, decb, mean, stdv, obs, (float*)d_out);
}